// Round 15
// baseline (246.368 us; speedup 1.0000x reference)
//
#include <hip/hip_runtime.h>
#include <stdint.h>

#define DEVINL __device__ __forceinline__

typedef short short8_t __attribute__((ext_vector_type(8)));
typedef float f32x4_t  __attribute__((ext_vector_type(4)));
typedef _Float16 half8_t __attribute__((ext_vector_type(8)));
typedef unsigned short u16;

static constexpr int  Bn = 8;
static constexpr int  Nn = 2048;
static constexpr int  Cn = 512;
static constexpr int  Mn = Bn * Nn;            // 16384
static constexpr long NC = (long)Nn * Cn;      // 1,048,576
static constexpr long NNe = (long)Nn * Nn;     // 4,194,304
static constexpr long CC = (long)Cn * Cn;      // 262,144
static constexpr long MC = (long)Mn * Cn;      // 8,388,608

DEVINL u16 f32_to_f16(float f) {
  _Float16 h = (_Float16)f;           // v_cvt_f16_f32 (RNE)
  u16 r; __builtin_memcpy(&r, &h, 2);
  return r;
}
DEVINL float f16_to_f32(u16 h) {
  _Float16 v; __builtin_memcpy(&v, &h, 2);
  return (float)v;
}

// MFMA via inline asm. A-frag: row=lane&15, k=(lane>>4)*8+j (contig 16B).
// B-frag: col=lane&15, same k. D: col=lane&15, row=(lane>>4)*4+reg. [guide §3, m89]
DEVINL void mfma_f16(f32x4_t& d, short8_t a, short8_t b) {
  asm("v_mfma_f32_16x16x32_f16 %0, %1, %2, %0" : "+v"(d) : "v"(a), "v"(b));
}

#define GLOAD_LDS16(G, L)                                                      \
  __builtin_amdgcn_global_load_lds(                                            \
      (const __attribute__((address_space(1))) void*)(G),                      \
      (__attribute__((address_space(3))) void*)(L), 16, 0, 0)

// ---------- fp32 -> f16 conversion ----------
__global__ __launch_bounds__(256) void conv_x_kernel(const float* __restrict__ src,
                                                     u16* __restrict__ f16, int n4) {
  int i = blockIdx.x * 256 + threadIdx.x;
  if (i >= n4) return;
  float4 v = ((const float4*)src)[i];
  ((ushort4*)f16)[i] = make_ushort4(f32_to_f16(v.x), f32_to_f16(v.y),
                                    f32_to_f16(v.z), f32_to_f16(v.w));
}

struct W5 { const float* p[5]; };
__global__ __launch_bounds__(256) void conv_w_kernel(W5 ws, u16* __restrict__ f16,
                                                     int n4each) {
  const int w = blockIdx.y;
  const int i = blockIdx.x * 256 + threadIdx.x;
  if (i >= n4each) return;
  float4 v = ((const float4*)ws.p[w])[i];
  ((ushort4*)f16)[(long)w * (CC / 4) + i] =
      make_ushort4(f32_to_f16(v.x), f32_to_f16(v.y), f32_to_f16(v.z), f32_to_f16(v.w));
}

// ---------- C = A * B^T GEMM: BM=BN=128, BK=64, 4 waves (64x64 each) ----------
// K-loop (r15): TRIPLE-buffered LDS, 2-tile lookahead -- steady state keeps
// tiles t+1,t+2 in flight (vmcnt(16)) while computing tile t.  1-tile
// lookahead left a (latency - compute) bubble per K-step (r13: 55% stall).
// LDS rows 128 B = 8 x 16B XOR-swizzled slots. [rule #21]
// Epilogues: r13's proven scalar form (r14's LDS-regroup regressed 25%).
// SW: 0 = XCD-owns-x-chunk; 1 = XCD-owns-batch (needs gz==8); 2 = identity.
enum { EPI_QKV = 0, EPI_SF16 = 2, EPI_PV = 3, EPI_RELU = 4, EPI_FFN2 = 5 };

template <int EPI, int SW>
__global__ __launch_bounds__(256, 1) void gemm_k(
    const u16* Ah, const u16* Bh,
    int K, int outld, void* out0, void* out1,
    const void* aux, const float* scal,
    int batch0, long azStride, long bzStride, long ozStride) {
  constexpr int BM = 128, BN = 128, BK = 64;
  constexpr int FM = 4, FN = 4;
  constexpr int ABYTES = BM * BK * 2;       // 16384
  constexpr int BBYTES = BN * BK * 2;       // 16384
  constexpr int PB = ABYTES + BBYTES;       // 32768

  __shared__ __align__(1024) char lds[3 * PB];   // 98304, 3-deep ring

  const int tid = threadIdx.x;
  const int l   = tid & 63;
  const int wid = tid >> 6;                 // 0..3

  int bx, byy, bz;
  {
    const int gx = gridDim.x, gy = gridDim.y, gz = gridDim.z;
    const int lid = blockIdx.x + gx * (blockIdx.y + gy * blockIdx.z);
    if (SW == 0) {
      const int c = lid & 7, s = lid >> 3;
      const int nyz = gy * gz;
      const int xi = s / nyz, yz = s - xi * nyz;
      bx = c + 8 * xi; byy = yz % gy; bz = yz / gy;
    } else if (SW == 1) {
      bz = lid & 7;
      const int s = lid >> 3;
      byy = s % gy; bx = s / gy;
    } else {
      bx = blockIdx.x; byy = blockIdx.y; bz = blockIdx.z;
    }
  }

  const int batch = batch0 + bz;
  const int brow  = bx * BM;
  const int bcol  = byy * BN;

  Ah += (long)bz * azStride;
  Bh += (long)bz * bzStride;

  const int wrL  = (wid >> 1) * 64;
  const int wcL  = (wid & 1) * 64;
  const int rsel = l & 15;

  f32x4_t acc[FM][FN];
  const f32x4_t zero = {0.f, 0.f, 0.f, 0.f};
#pragma unroll
  for (int m = 0; m < FM; ++m)
#pragma unroll
    for (int n = 0; n < FN; ++n) acc[m][n] = zero;

  // staging: one gload_lds issue = 1024 B = 8 rows x 128 B per wave (8/wave total).
  const int cb = ((l & 7) ^ ((l >> 3) & 7)) * 8;
  auto stageA = [&](int k0, char* dst) {
#pragma unroll
    for (int j = 0; j < 4; ++j) {
      const int rr = (wid * 4 + j) * 8 + (l >> 3);
      GLOAD_LDS16(Ah + (long)(brow + rr) * K + (k0 + cb), dst + (wid * 4 + j) * 1024);
    }
  };
  auto stageB = [&](int k0, char* dst) {
#pragma unroll
    for (int j = 0; j < 4; ++j) {
      const int rr = (wid * 4 + j) * 8 + (l >> 3);
      GLOAD_LDS16(Bh + (long)(bcol + rr) * K + (k0 + cb), dst + (wid * 4 + j) * 1024);
    }
  };
  auto stageAll = [&](int k0, char* b) { stageA(k0, b); stageB(k0, b + ABYTES); };

  auto rdA = [&](const char* bufA, int m, int ks) -> short8_t {
    const int r = wrL + m * 16 + rsel;
    const int s = ks * 4 + (l >> 4);
    return *(const short8_t*)(bufA + r * 128 + ((s ^ (r & 7)) << 4));
  };
  auto rdB = [&](const char* bufB, int n, int ks) -> short8_t {
    const int r = wcL + n * 16 + rsel;
    const int s = ks * 4 + (l >> 4);
    return *(const short8_t*)(bufB + r * 128 + ((s ^ (r & 7)) << 4));
  };

  const int NT = K >> 6;
  // Prologue: 2 tiles in flight.
  stageAll(0, lds);
  if (NT > 1) stageAll(1 << 6, lds + PB);
  int bufSel = 0;  // buffer index of tile t (mod-3 ring, tracked incrementally)
  for (int kt = 0; kt < NT; ++kt) {
    const char* bb = lds + bufSel * PB;
    if (kt + 2 < NT) {
      int nb = bufSel + 2; if (nb >= 3) nb -= 3;
      stageAll((kt + 2) << 6, lds + nb * PB);
      __builtin_amdgcn_sched_barrier(0);
      asm volatile("s_waitcnt vmcnt(16)" ::: "memory");   // t landed; t+1,t+2 in flight
    } else if (kt + 1 < NT) {
      __builtin_amdgcn_sched_barrier(0);
      asm volatile("s_waitcnt vmcnt(8)" ::: "memory");    // t landed; t+1 in flight
    } else {
      __builtin_amdgcn_sched_barrier(0);
      asm volatile("s_waitcnt vmcnt(0)" ::: "memory");    // last tile
    }
    __builtin_amdgcn_sched_barrier(0);
    __builtin_amdgcn_s_barrier();
    asm volatile("" ::: "memory");
    __builtin_amdgcn_sched_barrier(0);

    short8_t bf[FN][2];
#pragma unroll
    for (int n = 0; n < FN; ++n)
#pragma unroll
      for (int ks = 0; ks < 2; ++ks) bf[n][ks] = rdB(bb + ABYTES, n, ks);

    __builtin_amdgcn_s_setprio(1);
#pragma unroll
    for (int m = 0; m < FM; ++m) {
      short8_t a0 = rdA(bb, m, 0);
      short8_t a1 = rdA(bb, m, 1);
#pragma unroll
      for (int n = 0; n < FN; ++n) {
        mfma_f16(acc[m][n], a0, bf[n][0]);
        mfma_f16(acc[m][n], a1, bf[n][1]);
      }
    }
    __builtin_amdgcn_s_setprio(0);

    __builtin_amdgcn_sched_barrier(0);
    asm volatile("" ::: "memory");
    __builtin_amdgcn_s_barrier();
    __builtin_amdgcn_sched_barrier(0);
    ++bufSel; if (bufSel == 3) bufSel = 0;
  }

  // ---- Epilogues (r13 proven). D mapping: col=lane&15, row=(lane>>4)*4+j.
  const float sc0 = scal ? scal[0] : 0.0f;
  const int crow = (l >> 4) * 4;
  const int ccol = l & 15;

  if (EPI == EPI_QKV && bcol >= 1024) {
    // v-zone: transpose 128x128 tile via LDS -> vT[b][c][n']
    constexpr int TPV = 136;   // 128 rows + 8 pad (u16)
    u16* t = (u16*)lds;        // 128*136*2 = 34816 B < 96 KB
    const long b = brow >> 11;
#pragma unroll
    for (int m = 0; m < FM; ++m)
#pragma unroll
      for (int n = 0; n < FN; ++n) {
        ushort4 pk = make_ushort4(f32_to_f16(acc[m][n][0]), f32_to_f16(acc[m][n][1]),
                                  f32_to_f16(acc[m][n][2]), f32_to_f16(acc[m][n][3]));
        *(ushort4*)&t[(wcL + n * 16 + ccol) * TPV + (wrL + m * 16 + crow)] = pk;
      }
    __syncthreads();
    const int colq = tid >> 1, hf = tid & 1;   // colq<128, 2 chunks of 64 rows
    const int cv = bcol - 1024 + colq;
    u16* dst = (u16*)out1 + ((b * Cn + cv) * (long)Nn + (brow & 2047) + hf * 64);
    const u16* srcT = &t[colq * TPV + hf * 64];
#pragma unroll
    for (int i = 0; i < 8; ++i)
      ((uint4*)dst)[i] = *(const uint4*)(srcT + i * 8);
    return;
  }

#pragma unroll
  for (int m = 0; m < FM; ++m)
#pragma unroll
    for (int n = 0; n < FN; ++n)
#pragma unroll
      for (int j = 0; j < 4; ++j) {
        const int r = brow + wrL + m * 16 + crow + j;
        const int c = bcol + wcL + n * 16 + ccol;
        const float v = acc[m][n][j];
        if (EPI == EPI_QKV) {
          // q (cols 0-511) / k (cols 512-1023), row-major f16
          ((u16*)out0)[(long)(c >> 9) * MC + (long)r * Cn + (c & 511)] = f32_to_f16(v);
        } else if (EPI == EPI_SF16) {
          ((u16*)out0 + (long)bz * ozStride)[(long)r * outld + c] = f32_to_f16(v);
        } else if (EPI == EPI_PV) {
          // o = gamma*att + x  (f16 residual read, f16 store)
          const long gi = ((long)batch * Nn + r) * Cn + c;
          const float xa = f16_to_f32(((const u16*)aux)[gi]);
          ((u16*)out1)[gi] = f32_to_f16(sc0 * v + xa);
        } else if (EPI == EPI_RELU) {
          const float val = v > 0.f ? v : 0.f;
          ((u16*)out0)[(long)r * outld + c] = f32_to_f16(val);
        } else {  // EPI_FFN2: out = beta*acc + o16 (f16 residual)
          const long gi = (long)r * Cn + c;
          const float oa = f16_to_f32(((const u16*)aux)[gi]);
          ((float*)out0)[gi] = sc0 * v + oa;
        }
      }
}

// ---------- row softmax on f16 scoresT, emit f16 attnT ----------
__global__ __launch_bounds__(256) void softmax_k(const u16* sc, u16* attn) {
  const long base = (long)blockIdx.y * NNe + (long)blockIdx.x * Nn;
  const int tid = threadIdx.x;
  const int l = tid & 63, wid = tid >> 6;
  half8_t v = ((const half8_t*)(sc + base))[tid];
  float f[8];
#pragma unroll
  for (int i = 0; i < 8; ++i) f[i] = (float)v[i];
  float mx = f[0];
#pragma unroll
  for (int i = 1; i < 8; ++i) mx = fmaxf(mx, f[i]);
#pragma unroll
  for (int o = 32; o > 0; o >>= 1) mx = fmaxf(mx, __shfl_xor(mx, o));
  __shared__ float red[8];
  if (l == 0) red[wid] = mx;
  __syncthreads();
  mx = fmaxf(fmaxf(red[0], red[1]), fmaxf(red[2], red[3]));
  float p[8];
  float s = 0.f;
#pragma unroll
  for (int i = 0; i < 8; ++i) { p[i] = __expf(f[i] - mx); s += p[i]; }
#pragma unroll
  for (int o = 32; o > 0; o >>= 1) s += __shfl_xor(s, o);
  if (l == 0) red[4 + wid] = s;
  __syncthreads();
  s = red[4] + red[5] + red[6] + red[7];
  const float inv = 1.0f / s;
  __align__(16) u16 o8[8];
#pragma unroll
  for (int i = 0; i < 8; ++i) o8[i] = f32_to_f16(p[i] * inv);
  ((uint4*)(attn + base))[tid] = *(const uint4*)o8;
}

extern "C" void kernel_launch(void* const* d_in, const int* in_sizes, int n_in,
                              void* d_out, int out_size, void* d_ws, size_t ws_size,
                              hipStream_t stream) {
  const float* x  = (const float*)d_in[0];
  const float* gamma = (const float*)d_in[6];
  const float* beta  = (const float*)d_in[7];
  float* out = (float*)d_out;

  char* ws = (char*)d_ws;
  size_t off = 0;
  auto alloc = [&](size_t bytes) {
    char* p = ws + off;
    off += (bytes + 1023) & ~(size_t)1023;
    return p;
  };
  u16* x16  = (u16*)alloc((size_t)MC * 2);
  u16* w16A = (u16*)alloc((size_t)5 * CC * 2);
  u16* qk16 = (u16*)alloc((size_t)2 * MC * 2);  // q then k, contiguous
  u16* vT   = (u16*)alloc((size_t)MC * 2);
  u16* o16  = (u16*)alloc((size_t)MC * 2);
  u16* h16  = (u16*)alloc((size_t)MC * 2);
  const size_t baseOff = off;

  // pick largest attention batch-chunk that fits ws (scoresT f16 + attnT f16)
  int zAtt = 8;
  while (zAtt > 1 &&
         baseOff + (size_t)zAtt * (NNe * 2 + 1024 + NNe * 2 + 1024) > ws_size)
    zAtt >>= 1;
  u16* scoresT = (u16*)alloc((size_t)zAtt * NNe * 2);
  u16* attnT   = (u16*)alloc((size_t)zAtt * NNe * 2);
  u16* q16 = qk16;
  u16* k16 = qk16 + (size_t)MC;

  // 1) f16 conversions
  conv_x_kernel<<<dim3(MC / 4 / 256), 256, 0, stream>>>(x, x16, MC / 4);
  W5 w5 = {{(const float*)d_in[1], (const float*)d_in[2], (const float*)d_in[3],
            (const float*)d_in[4], (const float*)d_in[5]}};
  conv_w_kernel<<<dim3(CC / 4 / 256, 5), 256, 0, stream>>>(w5, w16A, CC / 4);

  // 2) merged qkv: [16384x512] x [1536x512]^T, 128x128 tiles
  gemm_k<EPI_QKV,0><<<dim3(Mn/128, 1536/128, 1), 256, 0, stream>>>(
      x16, w16A, Cn, Cn, qk16, vT, nullptr, nullptr, 0, 0, 0, 0);

  if (zAtt == 8) {
    // 3) attention one-shot, XCD-owns-batch
    gemm_k<EPI_SF16,1><<<dim3(Nn/128, Nn/128, 8), 256, 0, stream>>>(
        k16, q16, Cn, Nn, scoresT, nullptr, nullptr, nullptr, 0, NC, NC, NNe);
    softmax_k<<<dim3(Nn, 8), 256, 0, stream>>>(scoresT, attnT);
    gemm_k<EPI_PV,1><<<dim3(Nn/128, Cn/128, 8), 256, 0, stream>>>(
        attnT, vT, Nn, Cn, nullptr, o16, x16, gamma, 0, NNe, NC, 0);
  } else {
    for (int b0 = 0; b0 < Bn; b0 += zAtt) {
      gemm_k<EPI_SF16,2><<<dim3(Nn/128, Nn/128, zAtt), 256, 0, stream>>>(
          k16 + (long)b0 * NC, q16 + (long)b0 * NC,
          Cn, Nn, scoresT, nullptr, nullptr, nullptr, b0, NC, NC, NNe);
      softmax_k<<<dim3(Nn, zAtt), 256, 0, stream>>>(scoresT, attnT);
      gemm_k<EPI_PV,2><<<dim3(Nn/128, Cn/128, zAtt), 256, 0, stream>>>(
          attnT, vT + (long)b0 * NC, Nn, Cn, nullptr, o16, x16, gamma,
          b0, NNe, NC, 0);
    }
  }

  // 4) FFN: h = relu(o@W1^T); out = beta*(h@W2^T) + o16
  gemm_k<EPI_RELU,0><<<dim3(Mn/128, Cn/128, 1), 256, 0, stream>>>(
      o16, w16A + 3 * CC, Cn, Cn, h16, nullptr, nullptr, nullptr, 0, 0, 0, 0);
  gemm_k<EPI_FFN2,0><<<dim3(Mn/128, Cn/128, 1), 256, 0, stream>>>(
      h16, w16A + 4 * CC, Cn, Cn, out, nullptr, o16, beta, 0, 0, 0, 0);
}

// Round 17
// 200.196 us; speedup vs baseline: 1.2306x; 1.2306x over previous
//
#include <hip/hip_runtime.h>
#include <stdint.h>

#define DEVINL __device__ __forceinline__

typedef short short8_t __attribute__((ext_vector_type(8)));
typedef float f32x4_t  __attribute__((ext_vector_type(4)));
typedef _Float16 half8_t __attribute__((ext_vector_type(8)));
typedef unsigned short u16;

static constexpr int  Bn = 8;
static constexpr int  Nn = 2048;
static constexpr int  Cn = 512;
static constexpr int  Mn = Bn * Nn;            // 16384
static constexpr long NC = (long)Nn * Cn;      // 1,048,576
static constexpr long NNe = (long)Nn * Nn;     // 4,194,304
static constexpr long CC = (long)Cn * Cn;      // 262,144
static constexpr long MC = (long)Mn * Cn;      // 8,388,608

DEVINL u16 f32_to_f16(float f) {
  _Float16 h = (_Float16)f;           // v_cvt_f16_f32 (RNE)
  u16 r; __builtin_memcpy(&r, &h, 2);
  return r;
}
DEVINL float f16_to_f32(u16 h) {
  _Float16 v; __builtin_memcpy(&v, &h, 2);
  return (float)v;
}

// MFMA via inline asm. A-frag: row=lane&15, k=(lane>>4)*8+j (contig 16B).
// B-frag: col=lane&15, same k. D: col=lane&15, row=(lane>>4)*4+reg. [guide §3, m89]
DEVINL void mfma_f16(f32x4_t& d, short8_t a, short8_t b) {
  asm("v_mfma_f32_16x16x32_f16 %0, %1, %2, %0" : "+v"(d) : "v"(a), "v"(b));
}

#define GLOAD_LDS16(G, L)                                                      \
  __builtin_amdgcn_global_load_lds(                                            \
      (const __attribute__((address_space(1))) void*)(G),                      \
      (__attribute__((address_space(3))) void*)(L), 16, 0, 0)

// ---------- fp32 -> f16 conversion ----------
__global__ __launch_bounds__(256) void conv_x_kernel(const float* __restrict__ src,
                                                     u16* __restrict__ f16, int n4) {
  int i = blockIdx.x * 256 + threadIdx.x;
  if (i >= n4) return;
  float4 v = ((const float4*)src)[i];
  ((ushort4*)f16)[i] = make_ushort4(f32_to_f16(v.x), f32_to_f16(v.y),
                                    f32_to_f16(v.z), f32_to_f16(v.w));
}

struct W5 { const float* p[5]; };
__global__ __launch_bounds__(256) void conv_w_kernel(W5 ws, u16* __restrict__ f16,
                                                     int n4each) {
  const int w = blockIdx.y;
  const int i = blockIdx.x * 256 + threadIdx.x;
  if (i >= n4each) return;
  float4 v = ((const float4*)ws.p[w])[i];
  ((ushort4*)f16)[(long)w * (CC / 4) + i] =
      make_ushort4(f32_to_f16(v.x), f32_to_f16(v.y), f32_to_f16(v.z), f32_to_f16(v.w));
}

// ---------- C = A * B^T GEMM: BM=BN=128, BK=64, 4 waves (64x64 each) ----------
// dbuf LDS = 64 KB -> 2 independent blocks/CU (cross-block overlap, m114).
// Sync skeleton: stage(next) -> counted vmcnt(8) -> barrier -> compute -> barrier.
// LDS rows 128 B = 8 x 16B XOR-swizzled slots (pre-swizzled global source,
// linear gload_lds dest; read applies same XOR). [rule #21]
// SW: 0 = XCD-owns-x-chunk; 1 = XCD-owns-batch (needs gz==8); 2 = identity.
enum { EPI_QKV = 0, EPI_SF16 = 2, EPI_PV = 3, EPI_RELU = 4, EPI_FFN2 = 5 };

template <int EPI, int SW>
__global__ __launch_bounds__(256, 2) void gemm_k(
    const u16* Ah, const u16* Bh,
    int K, int outld, void* out0, void* out1,
    const void* aux, const float* scal,
    int batch0, long azStride, long bzStride, long ozStride) {
  constexpr int BM = 128, BN = 128, BK = 64;
  constexpr int FM = 4, FN = 4;
  constexpr int ABYTES = BM * BK * 2;       // 16384
  constexpr int BBYTES = BN * BK * 2;       // 16384
  constexpr int PB = ABYTES + BBYTES;       // 32768

  __shared__ __align__(1024) char lds[2 * PB];   // 65536

  const int tid = threadIdx.x;
  const int l   = tid & 63;
  const int wid = tid >> 6;                 // 0..3

  int bx, byy, bz;
  {
    const int gx = gridDim.x, gy = gridDim.y, gz = gridDim.z;
    const int lid = blockIdx.x + gx * (blockIdx.y + gy * blockIdx.z);
    if (SW == 0) {
      const int c = lid & 7, s = lid >> 3;
      const int nyz = gy * gz;
      const int xi = s / nyz, yz = s - xi * nyz;
      bx = c + 8 * xi; byy = yz % gy; bz = yz / gy;
    } else if (SW == 1) {
      bz = lid & 7;
      const int s = lid >> 3;
      byy = s % gy; bx = s / gy;
    } else {
      bx = blockIdx.x; byy = blockIdx.y; bz = blockIdx.z;
    }
  }

  const int batch = batch0 + bz;
  const int brow  = bx * BM;
  const int bcol  = byy * BN;

  Ah += (long)bz * azStride;
  Bh += (long)bz * bzStride;

  const int wrL  = (wid >> 1) * 64;
  const int wcL  = (wid & 1) * 64;
  const int rsel = l & 15;

  f32x4_t acc[FM][FN];
  const f32x4_t zero = {0.f, 0.f, 0.f, 0.f};
#pragma unroll
  for (int m = 0; m < FM; ++m)
#pragma unroll
    for (int n = 0; n < FN; ++n) acc[m][n] = zero;

  // staging: one gload_lds issue = 1024 B = 8 rows x 128 B per wave.
  const int cb = ((l & 7) ^ ((l >> 3) & 7)) * 8;
  auto stageA = [&](int k0, char* dst) {
#pragma unroll
    for (int j = 0; j < 4; ++j) {
      const int rr = (wid * 4 + j) * 8 + (l >> 3);
      GLOAD_LDS16(Ah + (long)(brow + rr) * K + (k0 + cb), dst + (wid * 4 + j) * 1024);
    }
  };
  auto stageB = [&](int k0, char* dst) {
#pragma unroll
    for (int j = 0; j < 4; ++j) {
      const int rr = (wid * 4 + j) * 8 + (l >> 3);
      GLOAD_LDS16(Bh + (long)(bcol + rr) * K + (k0 + cb), dst + (wid * 4 + j) * 1024);
    }
  };
  auto stageAll = [&](int k0, char* b) { stageA(k0, b); stageB(k0, b + ABYTES); };

  auto rdA = [&](const char* bufA, int m, int ks) -> short8_t {
    const int r = wrL + m * 16 + rsel;
    const int s = ks * 4 + (l >> 4);
    return *(const short8_t*)(bufA + r * 128 + ((s ^ (r & 7)) << 4));
  };
  auto rdB = [&](const char* bufB, int n, int ks) -> short8_t {
    const int r = wcL + n * 16 + rsel;
    const int s = ks * 4 + (l >> 4);
    return *(const short8_t*)(bufB + r * 128 + ((s ^ (r & 7)) << 4));
  };

  const int NT = K >> 6;
  stageAll(0, lds);
  for (int kt = 0; kt < NT; ++kt) {
    const char* bb = lds + (kt & 1) * PB;
    if (kt + 1 < NT) {
      stageAll((kt + 1) << 6, lds + ((kt + 1) & 1) * PB);
      __builtin_amdgcn_sched_barrier(0);
      asm volatile("s_waitcnt vmcnt(8)" ::: "memory");
    } else {
      __builtin_amdgcn_sched_barrier(0);
      asm volatile("s_waitcnt vmcnt(0)" ::: "memory");
    }
    __builtin_amdgcn_sched_barrier(0);
    __builtin_amdgcn_s_barrier();
    asm volatile("" ::: "memory");
    __builtin_amdgcn_sched_barrier(0);

    short8_t bf[FN][2];
#pragma unroll
    for (int n = 0; n < FN; ++n)
#pragma unroll
      for (int ks = 0; ks < 2; ++ks) bf[n][ks] = rdB(bb + ABYTES, n, ks);

    __builtin_amdgcn_s_setprio(1);
#pragma unroll
    for (int m = 0; m < FM; ++m) {
      short8_t a0 = rdA(bb, m, 0);
      short8_t a1 = rdA(bb, m, 1);
#pragma unroll
      for (int n = 0; n < FN; ++n) {
        mfma_f16(acc[m][n], a0, bf[n][0]);
        mfma_f16(acc[m][n], a1, bf[n][1]);
      }
    }
    __builtin_amdgcn_s_setprio(0);

    __builtin_amdgcn_sched_barrier(0);
    asm volatile("" ::: "memory");
    __builtin_amdgcn_s_barrier();
    __builtin_amdgcn_sched_barrier(0);
  }

  // ---- Epilogue. D mapping: col=lane&15, row=(lane>>4)*4+j.
  const float sc0 = scal ? scal[0] : 0.0f;
  const int crow = (l >> 4) * 4;
  const int ccol = l & 15;

  if (EPI == EPI_QKV && bcol >= 1024) {
    // v-zone: transpose 128x128 tile via LDS -> vT[b][c][n']
    constexpr int TPV = 136;   // 128 rows + 8 pad (u16)
    u16* t = (u16*)lds;        // 128*136*2 = 34816 B < 64 KB
    const long b = brow >> 11;
#pragma unroll
    for (int m = 0; m < FM; ++m)
#pragma unroll
      for (int n = 0; n < FN; ++n) {
        ushort4 pk = make_ushort4(f32_to_f16(acc[m][n][0]), f32_to_f16(acc[m][n][1]),
                                  f32_to_f16(acc[m][n][2]), f32_to_f16(acc[m][n][3]));
        *(ushort4*)&t[(wcL + n * 16 + ccol) * TPV + (wrL + m * 16 + crow)] = pk;
      }
    __syncthreads();
    const int colq = tid >> 1, hf = tid & 1;   // colq<128, 2 chunks of 64 rows
    const int cv = bcol - 1024 + colq;
    u16* dst = (u16*)out1 + ((b * Cn + cv) * (long)Nn + (brow & 2047) + hf * 64);
    const u16* srcT = &t[colq * TPV + hf * 64];
#pragma unroll
    for (int i = 0; i < 8; ++i)
      ((uint4*)dst)[i] = *(const uint4*)(srcT + i * 8);
    return;
  }

#pragma unroll
  for (int m = 0; m < FM; ++m)
#pragma unroll
    for (int n = 0; n < FN; ++n)
#pragma unroll
      for (int j = 0; j < 4; ++j) {
        const int r = brow + wrL + m * 16 + crow + j;
        const int c = bcol + wcL + n * 16 + ccol;
        const float v = acc[m][n][j];
        if (EPI == EPI_QKV) {
          // q (cols 0-511) / k (cols 512-1023), row-major f16
          ((u16*)out0)[(long)(c >> 9) * MC + (long)r * Cn + (c & 511)] = f32_to_f16(v);
        } else if (EPI == EPI_SF16) {
          ((u16*)out0 + (long)bz * ozStride)[(long)r * outld + c] = f32_to_f16(v);
        } else if (EPI == EPI_PV) {
          // o = gamma*att + x  (f16 residual read, f16 store)
          const long gi = ((long)batch * Nn + r) * Cn + c;
          const float xa = f16_to_f32(((const u16*)aux)[gi]);
          ((u16*)out1)[gi] = f32_to_f16(sc0 * v + xa);
        } else if (EPI == EPI_RELU) {
          const float val = v > 0.f ? v : 0.f;
          ((u16*)out0)[(long)r * outld + c] = f32_to_f16(val);
        } else {  // EPI_FFN2: out = beta*acc + o16 (f16 residual)
          const long gi = (long)r * Cn + c;
          const float oa = f16_to_f32(((const u16*)aux)[gi]);
          ((float*)out0)[gi] = sc0 * v + oa;
        }
      }
}

// ---------- row softmax on f16 scoresT, emit f16 attnT ----------
__global__ __launch_bounds__(256) void softmax_k(const u16* sc, u16* attn) {
  const long base = (long)blockIdx.y * NNe + (long)blockIdx.x * Nn;
  const int tid = threadIdx.x;
  const int l = tid & 63, wid = tid >> 6;
  half8_t v = ((const half8_t*)(sc + base))[tid];
  float f[8];
#pragma unroll
  for (int i = 0; i < 8; ++i) f[i] = (float)v[i];
  float mx = f[0];
#pragma unroll
  for (int i = 1; i < 8; ++i) mx = fmaxf(mx, f[i]);
#pragma unroll
  for (int o = 32; o > 0; o >>= 1) mx = fmaxf(mx, __shfl_xor(mx, o));
  __shared__ float red[8];
  if (l == 0) red[wid] = mx;
  __syncthreads();
  mx = fmaxf(fmaxf(red[0], red[1]), fmaxf(red[2], red[3]));
  float p[8];
  float s = 0.f;
#pragma unroll
  for (int i = 0; i < 8; ++i) { p[i] = __expf(f[i] - mx); s += p[i]; }
#pragma unroll
  for (int o = 32; o > 0; o >>= 1) s += __shfl_xor(s, o);
  if (l == 0) red[4 + wid] = s;
  __syncthreads();
  s = red[4] + red[5] + red[6] + red[7];
  const float inv = 1.0f / s;
  __align__(16) u16 o8[8];
#pragma unroll
  for (int i = 0; i < 8; ++i) o8[i] = f32_to_f16(p[i] * inv);
  ((uint4*)(attn + base))[tid] = *(const uint4*)o8;
}

extern "C" void kernel_launch(void* const* d_in, const int* in_sizes, int n_in,
                              void* d_out, int out_size, void* d_ws, size_t ws_size,
                              hipStream_t stream) {
  const float* x  = (const float*)d_in[0];
  const float* gamma = (const float*)d_in[6];
  const float* beta  = (const float*)d_in[7];
  float* out = (float*)d_out;

  char* ws = (char*)d_ws;
  size_t off = 0;
  auto alloc = [&](size_t bytes) {
    char* p = ws + off;
    off += (bytes + 1023) & ~(size_t)1023;
    return p;
  };
  u16* x16  = (u16*)alloc((size_t)MC * 2);
  u16* w16A = (u16*)alloc((size_t)5 * CC * 2);
  u16* qk16 = (u16*)alloc((size_t)2 * MC * 2);  // q then k, contiguous
  u16* vT   = (u16*)alloc((size_t)MC * 2);
  u16* o16  = (u16*)alloc((size_t)MC * 2);
  u16* h16  = (u16*)alloc((size_t)MC * 2);
  const size_t baseOff = off;

  // pick largest attention batch-chunk that fits ws (scoresT f16 + attnT f16)
  int zAtt = 8;
  while (zAtt > 1 &&
         baseOff + (size_t)zAtt * (NNe * 2 + 1024 + NNe * 2 + 1024) > ws_size)
    zAtt >>= 1;
  u16* scoresT = (u16*)alloc((size_t)zAtt * NNe * 2);
  u16* attnT   = (u16*)alloc((size_t)zAtt * NNe * 2);
  u16* q16 = qk16;
  u16* k16 = qk16 + (size_t)MC;

  // 1) f16 conversions
  conv_x_kernel<<<dim3(MC / 4 / 256), 256, 0, stream>>>(x, x16, MC / 4);
  W5 w5 = {{(const float*)d_in[1], (const float*)d_in[2], (const float*)d_in[3],
            (const float*)d_in[4], (const float*)d_in[5]}};
  conv_w_kernel<<<dim3(CC / 4 / 256, 5), 256, 0, stream>>>(w5, w16A, CC / 4);

  // 2) merged qkv: [16384x512] x [1536x512]^T, 128x128 tiles
  gemm_k<EPI_QKV,0><<<dim3(Mn/128, 1536/128, 1), 256, 0, stream>>>(
      x16, w16A, Cn, Cn, qk16, vT, nullptr, nullptr, 0, 0, 0, 0);

  if (zAtt == 8) {
    // 3) attention one-shot, XCD-owns-batch
    gemm_k<EPI_SF16,1><<<dim3(Nn/128, Nn/128, 8), 256, 0, stream>>>(
        k16, q16, Cn, Nn, scoresT, nullptr, nullptr, nullptr, 0, NC, NC, NNe);
    softmax_k<<<dim3(Nn, 8), 256, 0, stream>>>(scoresT, attnT);
    gemm_k<EPI_PV,1><<<dim3(Nn/128, Cn/128, 8), 256, 0, stream>>>(
        attnT, vT, Nn, Cn, nullptr, o16, x16, gamma, 0, NNe, NC, 0);
  } else {
    for (int b0 = 0; b0 < Bn; b0 += zAtt) {
      gemm_k<EPI_SF16,2><<<dim3(Nn/128, Nn/128, zAtt), 256, 0, stream>>>(
          k16 + (long)b0 * NC, q16 + (long)b0 * NC,
          Cn, Nn, scoresT, nullptr, nullptr, nullptr, b0, NC, NC, NNe);
      softmax_k<<<dim3(Nn, zAtt), 256, 0, stream>>>(scoresT, attnT);
      gemm_k<EPI_PV,2><<<dim3(Nn/128, Cn/128, zAtt), 256, 0, stream>>>(
          attnT, vT + (long)b0 * NC, Nn, Cn, nullptr, o16, x16, gamma,
          b0, NNe, NC, 0);
    }
  }

  // 4) FFN: h = relu(o@W1^T); out = beta*(h@W2^T) + o16
  gemm_k<EPI_RELU,0><<<dim3(Mn/128, Cn/128, 1), 256, 0, stream>>>(
      o16, w16A + 3 * CC, Cn, Cn, h16, nullptr, nullptr, nullptr, 0, 0, 0, 0);
  gemm_k<EPI_FFN2,0><<<dim3(Mn/128, Cn/128, 1), 256, 0, stream>>>(
      h16, w16A + 4 * CC, Cn, Cn, out, nullptr, o16, beta, 0, 0, 0, 0);
}

// Round 18
// 199.762 us; speedup vs baseline: 1.2333x; 1.0022x over previous
//
#include <hip/hip_runtime.h>
#include <stdint.h>

#define DEVINL __device__ __forceinline__

typedef short short8_t __attribute__((ext_vector_type(8)));
typedef float f32x4_t  __attribute__((ext_vector_type(4)));
typedef _Float16 half8_t __attribute__((ext_vector_type(8)));
typedef unsigned short u16;

static constexpr int  Bn = 8;
static constexpr int  Nn = 2048;
static constexpr int  Cn = 512;
static constexpr int  Mn = Bn * Nn;            // 16384
static constexpr long NC = (long)Nn * Cn;      // 1,048,576
static constexpr long NNe = (long)Nn * Nn;     // 4,194,304
static constexpr long CC = (long)Cn * Cn;      // 262,144
static constexpr long MC = (long)Mn * Cn;      // 8,388,608

DEVINL u16 f32_to_f16(float f) {
  _Float16 h = (_Float16)f;           // v_cvt_f16_f32 (RNE)
  u16 r; __builtin_memcpy(&r, &h, 2);
  return r;
}
DEVINL float f16_to_f32(u16 h) {
  _Float16 v; __builtin_memcpy(&v, &h, 2);
  return (float)v;
}

// MFMA via inline asm. A-frag: row=lane&15, k=(lane>>4)*8+j (contig 16B).
// B-frag: col=lane&15, same k. D: col=lane&15, row=(lane>>4)*4+reg. [guide §3, m89]
DEVINL void mfma_f16(f32x4_t& d, short8_t a, short8_t b) {
  asm("v_mfma_f32_16x16x32_f16 %0, %1, %2, %0" : "+v"(d) : "v"(a), "v"(b));
}

#define GLOAD_LDS16(G, L)                                                      \
  __builtin_amdgcn_global_load_lds(                                            \
      (const __attribute__((address_space(1))) void*)(G),                      \
      (__attribute__((address_space(3))) void*)(L), 16, 0, 0)

// ---------- fp32 -> f16 conversion ----------
__global__ __launch_bounds__(256) void conv_x_kernel(const float* __restrict__ src,
                                                     u16* __restrict__ f16, int n4) {
  int i = blockIdx.x * 256 + threadIdx.x;
  if (i >= n4) return;
  float4 v = ((const float4*)src)[i];
  ((ushort4*)f16)[i] = make_ushort4(f32_to_f16(v.x), f32_to_f16(v.y),
                                    f32_to_f16(v.z), f32_to_f16(v.w));
}

struct W5 { const float* p[5]; };
__global__ __launch_bounds__(256) void conv_w_kernel(W5 ws, u16* __restrict__ f16,
                                                     int n4each) {
  const int w = blockIdx.y;
  const int i = blockIdx.x * 256 + threadIdx.x;
  if (i >= n4each) return;
  float4 v = ((const float4*)ws.p[w])[i];
  ((ushort4*)f16)[(long)w * (CC / 4) + i] =
      make_ushort4(f32_to_f16(v.x), f32_to_f16(v.y), f32_to_f16(v.z), f32_to_f16(v.w));
}

// ---------- C = A * B^T GEMM: BM=BN=128, BK=64, 4 waves (64x64 each) ----------
// dbuf LDS = 64 KB -> 2 independent blocks/CU (cross-block overlap, m114).
// Sync skeleton: stage(next) -> counted vmcnt(8) -> barrier -> compute -> barrier.
// LDS rows 128 B = 8 x 16B XOR-swizzled slots (pre-swizzled global source,
// linear gload_lds dest; read applies same XOR). [rule #21]
// SW: 0 = XCD-owns-x-chunk; 1 = XCD-owns-batch (needs gz==8); 2 = identity.
enum { EPI_QKV = 0, EPI_SF16 = 2, EPI_PV = 3, EPI_RELU = 4, EPI_FFN2 = 5 };

template <int EPI, int SW>
__global__ __launch_bounds__(256, 2) void gemm_k(
    const u16* Ah, const u16* Bh,
    int K, int outld, void* out0, void* out1,
    const void* aux, const float* scal,
    int batch0, long azStride, long bzStride, long ozStride) {
  constexpr int BM = 128, BN = 128, BK = 64;
  constexpr int FM = 4, FN = 4;
  constexpr int ABYTES = BM * BK * 2;       // 16384
  constexpr int BBYTES = BN * BK * 2;       // 16384
  constexpr int PB = ABYTES + BBYTES;       // 32768

  __shared__ __align__(1024) char lds[2 * PB];   // 65536

  const int tid = threadIdx.x;
  const int l   = tid & 63;
  const int wid = tid >> 6;                 // 0..3

  int bx, byy, bz;
  {
    const int gx = gridDim.x, gy = gridDim.y, gz = gridDim.z;
    const int lid = blockIdx.x + gx * (blockIdx.y + gy * blockIdx.z);
    if (SW == 0) {
      const int c = lid & 7, s = lid >> 3;
      const int nyz = gy * gz;
      const int xi = s / nyz, yz = s - xi * nyz;
      bx = c + 8 * xi; byy = yz % gy; bz = yz / gy;
    } else if (SW == 1) {
      bz = lid & 7;
      const int s = lid >> 3;
      byy = s % gy; bx = s / gy;
    } else {
      bx = blockIdx.x; byy = blockIdx.y; bz = blockIdx.z;
    }
  }

  const int batch = batch0 + bz;
  const int brow  = bx * BM;
  const int bcol  = byy * BN;

  Ah += (long)bz * azStride;
  Bh += (long)bz * bzStride;

  const int wrL  = (wid >> 1) * 64;
  const int wcL  = (wid & 1) * 64;
  const int rsel = l & 15;

  f32x4_t acc[FM][FN];
  const f32x4_t zero = {0.f, 0.f, 0.f, 0.f};
#pragma unroll
  for (int m = 0; m < FM; ++m)
#pragma unroll
    for (int n = 0; n < FN; ++n) acc[m][n] = zero;

  // staging: one gload_lds issue = 1024 B = 8 rows x 128 B per wave.
  const int cb = ((l & 7) ^ ((l >> 3) & 7)) * 8;
  auto stageA = [&](int k0, char* dst) {
#pragma unroll
    for (int j = 0; j < 4; ++j) {
      const int rr = (wid * 4 + j) * 8 + (l >> 3);
      GLOAD_LDS16(Ah + (long)(brow + rr) * K + (k0 + cb), dst + (wid * 4 + j) * 1024);
    }
  };
  auto stageB = [&](int k0, char* dst) {
#pragma unroll
    for (int j = 0; j < 4; ++j) {
      const int rr = (wid * 4 + j) * 8 + (l >> 3);
      GLOAD_LDS16(Bh + (long)(bcol + rr) * K + (k0 + cb), dst + (wid * 4 + j) * 1024);
    }
  };
  auto stageAll = [&](int k0, char* b) { stageA(k0, b); stageB(k0, b + ABYTES); };

  auto rdA = [&](const char* bufA, int m, int ks) -> short8_t {
    const int r = wrL + m * 16 + rsel;
    const int s = ks * 4 + (l >> 4);
    return *(const short8_t*)(bufA + r * 128 + ((s ^ (r & 7)) << 4));
  };
  auto rdB = [&](const char* bufB, int n, int ks) -> short8_t {
    const int r = wcL + n * 16 + rsel;
    const int s = ks * 4 + (l >> 4);
    return *(const short8_t*)(bufB + r * 128 + ((s ^ (r & 7)) << 4));
  };

  const int NT = K >> 6;
  stageAll(0, lds);
  for (int kt = 0; kt < NT; ++kt) {
    const char* bb = lds + (kt & 1) * PB;
    if (kt + 1 < NT) {
      stageAll((kt + 1) << 6, lds + ((kt + 1) & 1) * PB);
      __builtin_amdgcn_sched_barrier(0);
      asm volatile("s_waitcnt vmcnt(8)" ::: "memory");
    } else {
      __builtin_amdgcn_sched_barrier(0);
      asm volatile("s_waitcnt vmcnt(0)" ::: "memory");
    }
    __builtin_amdgcn_sched_barrier(0);
    __builtin_amdgcn_s_barrier();
    asm volatile("" ::: "memory");
    __builtin_amdgcn_sched_barrier(0);

    short8_t bf[FN][2];
#pragma unroll
    for (int n = 0; n < FN; ++n)
#pragma unroll
      for (int ks = 0; ks < 2; ++ks) bf[n][ks] = rdB(bb + ABYTES, n, ks);

    __builtin_amdgcn_s_setprio(1);
#pragma unroll
    for (int m = 0; m < FM; ++m) {
      short8_t a0 = rdA(bb, m, 0);
      short8_t a1 = rdA(bb, m, 1);
#pragma unroll
      for (int n = 0; n < FN; ++n) {
        mfma_f16(acc[m][n], a0, bf[n][0]);
        mfma_f16(acc[m][n], a1, bf[n][1]);
      }
    }
    __builtin_amdgcn_s_setprio(0);

    __builtin_amdgcn_sched_barrier(0);
    asm volatile("" ::: "memory");
    __builtin_amdgcn_s_barrier();
    __builtin_amdgcn_sched_barrier(0);
  }

  // ---- Epilogue. D mapping: col=lane&15, row=(lane>>4)*4+j.
  const float sc0 = scal ? scal[0] : 0.0f;
  const int crow = (l >> 4) * 4;
  const int ccol = l & 15;

  if (EPI == EPI_QKV && bcol >= 1024) {
    // v-zone: transpose 128x128 tile via LDS -> vT[b][c][n']
    constexpr int TPV = 136;   // 128 rows + 8 pad (u16)
    u16* t = (u16*)lds;        // 128*136*2 = 34816 B < 64 KB
    const long b = brow >> 11;
#pragma unroll
    for (int m = 0; m < FM; ++m)
#pragma unroll
      for (int n = 0; n < FN; ++n) {
        ushort4 pk = make_ushort4(f32_to_f16(acc[m][n][0]), f32_to_f16(acc[m][n][1]),
                                  f32_to_f16(acc[m][n][2]), f32_to_f16(acc[m][n][3]));
        *(ushort4*)&t[(wcL + n * 16 + ccol) * TPV + (wrL + m * 16 + crow)] = pk;
      }
    __syncthreads();
    const int colq = tid >> 1, hf = tid & 1;   // colq<128, 2 chunks of 64 rows
    const int cv = bcol - 1024 + colq;
    u16* dst = (u16*)out1 + ((b * Cn + cv) * (long)Nn + (brow & 2047) + hf * 64);
    const u16* srcT = &t[colq * TPV + hf * 64];
#pragma unroll
    for (int i = 0; i < 8; ++i)
      ((uint4*)dst)[i] = *(const uint4*)(srcT + i * 8);
    return;
  }

#pragma unroll
  for (int m = 0; m < FM; ++m)
#pragma unroll
    for (int n = 0; n < FN; ++n)
#pragma unroll
      for (int j = 0; j < 4; ++j) {
        const int r = brow + wrL + m * 16 + crow + j;
        const int c = bcol + wcL + n * 16 + ccol;
        const float v = acc[m][n][j];
        if (EPI == EPI_QKV) {
          // q (cols 0-511) / k (cols 512-1023), row-major f16
          ((u16*)out0)[(long)(c >> 9) * MC + (long)r * Cn + (c & 511)] = f32_to_f16(v);
        } else if (EPI == EPI_SF16) {
          ((u16*)out0 + (long)bz * ozStride)[(long)r * outld + c] = f32_to_f16(v);
        } else if (EPI == EPI_PV) {
          // o = gamma*att + x  (f16 residual read, f16 store)
          const long gi = ((long)batch * Nn + r) * Cn + c;
          const float xa = f16_to_f32(((const u16*)aux)[gi]);
          ((u16*)out1)[gi] = f32_to_f16(sc0 * v + xa);
        } else if (EPI == EPI_RELU) {
          const float val = v > 0.f ? v : 0.f;
          ((u16*)out0)[(long)r * outld + c] = f32_to_f16(val);
        } else {  // EPI_FFN2: out = beta*acc + o16 (f16 residual)
          const long gi = (long)r * Cn + c;
          const float oa = f16_to_f32(((const u16*)aux)[gi]);
          ((float*)out0)[gi] = sc0 * v + oa;
        }
      }
}

// ---------- row softmax on f16 scoresT, emit f16 attnT ----------
// 1-D grid of Nn*zAtt blocks; decode b = lid % zAtt, j = lid / zAtt.
// For zAtt==8 this pins batch b to XCD b (lid&7 round-robin), aligning the
// scores(SW=1) -> softmax -> PV(SW=1) chain in one XCD's L2.
__global__ __launch_bounds__(256) void softmax_k(const u16* sc, u16* attn) {
  const int zA = gridDim.x >> 11;           // gridDim.x = 2048 * zAtt
  const int lid = blockIdx.x;
  const int jrow = lid / zA;
  const int b = lid - jrow * zA;
  const long base = (long)b * NNe + (long)jrow * Nn;
  const int tid = threadIdx.x;
  const int l = tid & 63, wid = tid >> 6;
  half8_t v = ((const half8_t*)(sc + base))[tid];
  float f[8];
#pragma unroll
  for (int i = 0; i < 8; ++i) f[i] = (float)v[i];
  float mx = f[0];
#pragma unroll
  for (int i = 1; i < 8; ++i) mx = fmaxf(mx, f[i]);
#pragma unroll
  for (int o = 32; o > 0; o >>= 1) mx = fmaxf(mx, __shfl_xor(mx, o));
  __shared__ float red[8];
  if (l == 0) red[wid] = mx;
  __syncthreads();
  mx = fmaxf(fmaxf(red[0], red[1]), fmaxf(red[2], red[3]));
  float p[8];
  float s = 0.f;
#pragma unroll
  for (int i = 0; i < 8; ++i) { p[i] = __expf(f[i] - mx); s += p[i]; }
#pragma unroll
  for (int o = 32; o > 0; o >>= 1) s += __shfl_xor(s, o);
  if (l == 0) red[4 + wid] = s;
  __syncthreads();
  s = red[4] + red[5] + red[6] + red[7];
  const float inv = 1.0f / s;
  __align__(16) u16 o8[8];
#pragma unroll
  for (int i = 0; i < 8; ++i) o8[i] = f32_to_f16(p[i] * inv);
  ((uint4*)(attn + base))[tid] = *(const uint4*)o8;
}

extern "C" void kernel_launch(void* const* d_in, const int* in_sizes, int n_in,
                              void* d_out, int out_size, void* d_ws, size_t ws_size,
                              hipStream_t stream) {
  const float* x  = (const float*)d_in[0];
  const float* gamma = (const float*)d_in[6];
  const float* beta  = (const float*)d_in[7];
  float* out = (float*)d_out;

  char* ws = (char*)d_ws;
  size_t off = 0;
  auto alloc = [&](size_t bytes) {
    char* p = ws + off;
    off += (bytes + 1023) & ~(size_t)1023;
    return p;
  };
  u16* x16  = (u16*)alloc((size_t)MC * 2);
  u16* w16A = (u16*)alloc((size_t)5 * CC * 2);
  u16* qk16 = (u16*)alloc((size_t)2 * MC * 2);  // q then k, contiguous
  u16* vT   = (u16*)alloc((size_t)MC * 2);
  u16* o16  = (u16*)alloc((size_t)MC * 2);
  u16* h16  = (u16*)alloc((size_t)MC * 2);
  const size_t baseOff = off;

  // pick largest attention batch-chunk that fits ws (scoresT f16 + attnT f16)
  int zAtt = 8;
  while (zAtt > 1 &&
         baseOff + (size_t)zAtt * (NNe * 2 + 1024 + NNe * 2 + 1024) > ws_size)
    zAtt >>= 1;
  u16* scoresT = (u16*)alloc((size_t)zAtt * NNe * 2);
  u16* attnT   = (u16*)alloc((size_t)zAtt * NNe * 2);
  u16* q16 = qk16;
  u16* k16 = qk16 + (size_t)MC;

  // 1) f16 conversions
  conv_x_kernel<<<dim3(MC / 4 / 256), 256, 0, stream>>>(x, x16, MC / 4);
  W5 w5 = {{(const float*)d_in[1], (const float*)d_in[2], (const float*)d_in[3],
            (const float*)d_in[4], (const float*)d_in[5]}};
  conv_w_kernel<<<dim3(CC / 4 / 256, 5), 256, 0, stream>>>(w5, w16A, CC / 4);

  // 2) merged qkv: [16384x512] x [1536x512]^T, 128x128 tiles
  gemm_k<EPI_QKV,0><<<dim3(Mn/128, 1536/128, 1), 256, 0, stream>>>(
      x16, w16A, Cn, Cn, qk16, vT, nullptr, nullptr, 0, 0, 0, 0);

  if (zAtt == 8) {
    // 3) attention one-shot, XCD-owns-batch end-to-end
    gemm_k<EPI_SF16,1><<<dim3(Nn/128, Nn/128, 8), 256, 0, stream>>>(
        k16, q16, Cn, Nn, scoresT, nullptr, nullptr, nullptr, 0, NC, NC, NNe);
    softmax_k<<<dim3(Nn * 8), 256, 0, stream>>>(scoresT, attnT);
    gemm_k<EPI_PV,1><<<dim3(Nn/128, Cn/128, 8), 256, 0, stream>>>(
        attnT, vT, Nn, Cn, nullptr, o16, x16, gamma, 0, NNe, NC, 0);
  } else {
    for (int b0 = 0; b0 < Bn; b0 += zAtt) {
      gemm_k<EPI_SF16,2><<<dim3(Nn/128, Nn/128, zAtt), 256, 0, stream>>>(
          k16 + (long)b0 * NC, q16 + (long)b0 * NC,
          Cn, Nn, scoresT, nullptr, nullptr, nullptr, b0, NC, NC, NNe);
      softmax_k<<<dim3(Nn * zAtt), 256, 0, stream>>>(scoresT, attnT);
      gemm_k<EPI_PV,2><<<dim3(Nn/128, Cn/128, zAtt), 256, 0, stream>>>(
          attnT, vT + (long)b0 * NC, Nn, Cn, nullptr, o16, x16, gamma,
          b0, NNe, NC, 0);
    }
  }

  // 4) FFN: h = relu(o@W1^T); out = beta*(h@W2^T) + o16
  gemm_k<EPI_RELU,0><<<dim3(Mn/128, Cn/128, 1), 256, 0, stream>>>(
      o16, w16A + 3 * CC, Cn, Cn, h16, nullptr, nullptr, nullptr, 0, 0, 0, 0);
  gemm_k<EPI_FFN2,0><<<dim3(Mn/128, Cn/128, 1), 256, 0, stream>>>(
      h16, w16A + 4 * CC, Cn, Cn, out, nullptr, o16, beta, 0, 0, 0, 0);
}